// Round 2
// baseline (213.675 us; speedup 1.0000x reference)
//
#include <hip/hip_runtime.h>
#include <hip/hip_bf16.h>

// Centroid update: per-class mean of embed rows, blended with old centroid.
//   out[c,:] = 0.3 * (sum_{i: y[i]==c} embed[i,:]) / count[c] + 0.7 * centroid[c,:]
//
// R2 structure: one block per class (1000 blocks, 256 threads, thread owns 4
// dims). Phase 1: barrier-free full scan of y (32 independent int4 loads per
// thread, deep vmcnt pipelining) building the COMPLETE row list in LDS via an
// atomic counter. ONE barrier. Phase 2: gather unrolled x8 so >=8 independent
// 4KB row loads are in flight per block (vs ~1 in R1's per-chunk-barrier
// version, which was latency-bound at 207us). embed read exactly once
// device-wide; y re-reads (1000 x 128KB) served by L2/L3.

#define BATCH       32768
#define EMBED_DIM   1024
#define NUM_CLASSES 1000
#define FACTOR      0.3f
#define MAXROWS     512   // per-class row capacity; actual max ~60 (mean 32.8)

__global__ __launch_bounds__(256) void centroid_kernel(
    const float* __restrict__ embed,
    const int*   __restrict__ y,
    const float* __restrict__ centroid,
    float*       __restrict__ out)
{
    const int c   = blockIdx.x;
    const int tid = threadIdx.x;

    __shared__ int rows[MAXROWS];
    __shared__ int nmatch;

    if (tid == 0) nmatch = 0;
    __syncthreads();

    // ---- Phase 1: full scan of y, no barriers, loads pipeline freely ----
    const int4* y4 = reinterpret_cast<const int4*>(y);
    #pragma unroll 4
    for (int it = 0; it < BATCH / 1024; ++it) {   // 32 iterations
        const int  i4   = it * 256 + tid;         // int4 index
        const int4 yv   = y4[i4];
        const int  base = i4 * 4;
        if (yv.x == c) { int p = atomicAdd(&nmatch, 1); rows[p] = base + 0; }
        if (yv.y == c) { int p = atomicAdd(&nmatch, 1); rows[p] = base + 1; }
        if (yv.z == c) { int p = atomicAdd(&nmatch, 1); rows[p] = base + 2; }
        if (yv.w == c) { int p = atomicAdd(&nmatch, 1); rows[p] = base + 3; }
    }
    __syncthreads();
    const int m = nmatch;

    // ---- Phase 2: gather matched rows, 8 independent loads in flight ----
    const int d = tid * 4;                        // this thread's dim offset
    float4 acc = make_float4(0.f, 0.f, 0.f, 0.f);

    int j = 0;
    for (; j + 8 <= m; j += 8) {
        const int r0 = rows[j+0], r1 = rows[j+1], r2 = rows[j+2], r3 = rows[j+3];
        const int r4 = rows[j+4], r5 = rows[j+5], r6 = rows[j+6], r7 = rows[j+7];
        const float4 v0 = *reinterpret_cast<const float4*>(embed + (size_t)r0 * EMBED_DIM + d);
        const float4 v1 = *reinterpret_cast<const float4*>(embed + (size_t)r1 * EMBED_DIM + d);
        const float4 v2 = *reinterpret_cast<const float4*>(embed + (size_t)r2 * EMBED_DIM + d);
        const float4 v3 = *reinterpret_cast<const float4*>(embed + (size_t)r3 * EMBED_DIM + d);
        const float4 v4 = *reinterpret_cast<const float4*>(embed + (size_t)r4 * EMBED_DIM + d);
        const float4 v5 = *reinterpret_cast<const float4*>(embed + (size_t)r5 * EMBED_DIM + d);
        const float4 v6 = *reinterpret_cast<const float4*>(embed + (size_t)r6 * EMBED_DIM + d);
        const float4 v7 = *reinterpret_cast<const float4*>(embed + (size_t)r7 * EMBED_DIM + d);
        acc.x += v0.x + v1.x + v2.x + v3.x + v4.x + v5.x + v6.x + v7.x;
        acc.y += v0.y + v1.y + v2.y + v3.y + v4.y + v5.y + v6.y + v7.y;
        acc.z += v0.z + v1.z + v2.z + v3.z + v4.z + v5.z + v6.z + v7.z;
        acc.w += v0.w + v1.w + v2.w + v3.w + v4.w + v5.w + v6.w + v7.w;
    }
    for (; j < m; ++j) {
        const int r = rows[j];
        const float4 v = *reinterpret_cast<const float4*>(embed + (size_t)r * EMBED_DIM + d);
        acc.x += v.x; acc.y += v.y; acc.z += v.z; acc.w += v.w;
    }

    // ---- Epilogue: mean, blend, store (count==0 -> NaN, matches ref) ----
    const float inv = 1.0f / (float)m;
    const size_t o  = (size_t)c * EMBED_DIM + d;
    const float4 cen = *reinterpret_cast<const float4*>(centroid + o);
    float4 res;
    res.x = FACTOR * (acc.x * inv) + (1.0f - FACTOR) * cen.x;
    res.y = FACTOR * (acc.y * inv) + (1.0f - FACTOR) * cen.y;
    res.z = FACTOR * (acc.z * inv) + (1.0f - FACTOR) * cen.z;
    res.w = FACTOR * (acc.w * inv) + (1.0f - FACTOR) * cen.w;
    *reinterpret_cast<float4*>(out + o) = res;
}

extern "C" void kernel_launch(void* const* d_in, const int* in_sizes, int n_in,
                              void* d_out, int out_size, void* d_ws, size_t ws_size,
                              hipStream_t stream) {
    const float* embed    = (const float*)d_in[0];  // [32768, 1024]
    const int*   y        = (const int*)d_in[1];    // [32768]
    const float* centroid = (const float*)d_in[2];  // [1000, 1024]
    float*       out      = (float*)d_out;          // [1000, 1024]

    centroid_kernel<<<NUM_CLASSES, 256, 0, stream>>>(embed, y, centroid, out);
}